// Round 5
// baseline (137.364 us; speedup 1.0000x reference)
//
#include <hip/hip_runtime.h>
#include <hip/hip_bf16.h>

// Problem dims (fixed by reference)
#define BB 4
#define ENC_LEN 1024
#define DEC_LEN 256
#define ENC_H 1024
#define ATTN_A 256

#define C2F 2.8853900817779268f  // 2*log2(e)

typedef short bf16x8 __attribute__((ext_vector_type(8)));
typedef float f32x4 __attribute__((ext_vector_type(4)));
typedef float f32x2 __attribute__((ext_vector_type(2)));
typedef unsigned int u32x2 __attribute__((ext_vector_type(2)));

union BF8 {
  uint4 q;
  bf16x8 v;
};

// fp32 -> bf16 round-to-nearest-even
static __device__ __forceinline__ unsigned short f2bf(float x) {
  union {
    float f;
    unsigned int u;
  } c;
  c.f = x;
  unsigned int r = c.u + 0x7FFFu + ((c.u >> 16) & 1u);
  return (unsigned short)(r >> 16);
}

// ---------------------------------------------------------------------------
// prep: weight transposes + row-major bf16 converts (1408 blocks).
//  [0,128):     Wh/Ws [1024h][256a] -> WhT/WsT bf16 [256a][1024h]  (LDS path)
//  [128,1152):  enc -> encB bf16 (flat convert, no LDS)
//  [1152,1408): dec -> decB bf16 (flat convert, no LDS)
// encT is NOT produced here anymore -- it's overlapped with logits (only
// cgemm consumes it), shortening the serial critical path.
// ---------------------------------------------------------------------------
__global__ __launch_bounds__(256) void prep_k(
    const float* __restrict__ Wh, const float* __restrict__ Ws,
    const float* __restrict__ enc, const float* __restrict__ dec,
    unsigned short* __restrict__ WhT, unsigned short* __restrict__ WsT,
    unsigned short* __restrict__ encB, unsigned short* __restrict__ decB) {
  __shared__ unsigned short T[64][68];
  const int wb = blockIdx.x;
  const int t = threadIdx.x;

  if (wb >= 128) {
    // flat fp32 -> bf16 convert: 4096 floats per block, coalesced
    const float* in;
    unsigned short* out;
    long base;
    if (wb < 1152) {
      in = enc;
      out = encB;
      base = (long)(wb - 128) * 4096;
    } else {
      in = dec;
      out = decB;
      base = (long)(wb - 1152) * 4096;
    }
#pragma unroll
    for (int k = 0; k < 4; ++k) {
      const long i = base + (long)(t + k * 256) * 4;
      const float4 v = *(const float4*)&in[i];
      ushort4 o;
      o.x = f2bf(v.x);
      o.y = f2bf(v.y);
      o.z = f2bf(v.z);
      o.w = f2bf(v.w);
      *(ushort4*)&out[i] = o;
    }
    return;
  }

  // weight transpose path (LDS tile)
  const int lr = t >> 4;
  const int lc4 = (t & 15) * 4;
  const float* in = (wb < 64) ? Wh : Ws;
  unsigned short* out = (wb < 64) ? WhT : WsT;
  const int tt = wb & 63;
  const int bx = tt & 3;
  const int by = tt >> 2;
  const int r0 = by * 64;
  const int c0 = bx * 64;

#pragma unroll
  for (int p = 0; p < 4; ++p) {
    const int r = lr + p * 16;
    const float4 v = *(const float4*)&in[(long)(r0 + r) * ATTN_A + c0 + lc4];
    ushort4 o;
    o.x = f2bf(v.x);
    o.y = f2bf(v.y);
    o.z = f2bf(v.z);
    o.w = f2bf(v.w);
    *(ushort4*)&T[r][lc4] = o;
  }
  __syncthreads();
#pragma unroll
  for (int p = 0; p < 4; ++p) {
    const int c = lr + p * 16;
    ushort4 o;
    o.x = T[lc4 + 0][c];
    o.y = T[lc4 + 1][c];
    o.z = T[lc4 + 2][c];
    o.w = T[lc4 + 3][c];
    *(ushort4*)&out[(long)(c0 + c) * ENC_H + r0 + lc4] = o;
  }
}

// ---------------------------------------------------------------------------
// Fused projection GEMM, full-K (1024), exp2 epilogue. 1-D grid, 320 blocks:
//  bid <  64:  Ed[bd][a]  = exp2(C2*(decB·WsT) + C2*bs[a])     [1024][256]
//  bid >= 64:  Ee[b][a][e] = exp2(C2*(WhT·encB^T))             [4][256][1024]
// Tile 64x64, BK=64, padded LDS [64][72] (16B-aligned rows -> ds_read_b128;
// bank stride 36 -> 2-way alias = free). All-bf16 operands (R3-proven).
// ---------------------------------------------------------------------------
__global__ __launch_bounds__(256) void pgemm(const unsigned short* __restrict__ decB,
                                             const unsigned short* __restrict__ encB,
                                             const unsigned short* __restrict__ WsT,
                                             const unsigned short* __restrict__ WhT,
                                             const float* __restrict__ bs,
                                             float* __restrict__ Ed,
                                             float* __restrict__ Ee) {
  __shared__ unsigned short As[64][72];
  __shared__ unsigned short Bs[64][72];

  const int bid = blockIdx.x;
  const bool isPD = bid < 64;
  const unsigned short* A;
  const unsigned short* BT;
  float* out;
  int ldc, m0, n0;
  if (isPD) {
    A = decB;
    BT = WsT;
    out = Ed;
    ldc = ATTN_A;
    m0 = (bid >> 2) * 64;
    n0 = (bid & 3) * 64;
  } else {
    const int q = bid - 64;
    const int b = q >> 6;
    const int r = q & 63;
    A = WhT;
    BT = encB + (long)b * ENC_LEN * ENC_H;
    out = Ee + (long)b * ATTN_A * ENC_LEN;
    ldc = ENC_LEN;
    m0 = (r >> 4) * 64;
    n0 = (r & 15) * 64;
  }

  const int tid = threadIdx.x;
  const int lane = tid & 63;
  const int wave = tid >> 6;
  const int quad = lane >> 4;
  const int l16 = lane & 15;
  const int wm = (wave >> 1) * 32;
  const int wn = (wave & 1) * 32;
  const int sr = tid >> 2;        // 0..63
  const int sk = (tid & 3) * 16;  // shorts: 0,16,32,48

  f32x4 acc[2][2] = {{{0.f, 0.f, 0.f, 0.f}, {0.f, 0.f, 0.f, 0.f}},
                     {{0.f, 0.f, 0.f, 0.f}, {0.f, 0.f, 0.f, 0.f}}};

  const unsigned short* Ap = A + (long)(m0 + sr) * ENC_H + sk;
  const unsigned short* Bp = BT + (long)(n0 + sr) * ENC_H + sk;

  uint4 a0 = *(const uint4*)(Ap);
  uint4 a1 = *(const uint4*)(Ap + 8);
  uint4 b0 = *(const uint4*)(Bp);
  uint4 b1 = *(const uint4*)(Bp + 8);

  for (int k0 = 0; k0 < 1024; k0 += 64) {
    __syncthreads();
    *(uint4*)&As[sr][sk] = a0;
    *(uint4*)&As[sr][sk + 8] = a1;
    *(uint4*)&Bs[sr][sk] = b0;
    *(uint4*)&Bs[sr][sk + 8] = b1;
    const int kn = (k0 + 64 < 1024) ? (k0 + 64) : 0;
    a0 = *(const uint4*)(Ap + kn);
    a1 = *(const uint4*)(Ap + kn + 8);
    b0 = *(const uint4*)(Bp + kn);
    b1 = *(const uint4*)(Bp + kn + 8);
    __syncthreads();

#pragma unroll
    for (int h = 0; h < 2; ++h) {
      bf16x8 af[2], bfr[2];
#pragma unroll
      for (int i = 0; i < 2; ++i) {
        BF8 t;
        t.q = *(const uint4*)&As[wm + i * 16 + l16][h * 32 + quad * 8];
        af[i] = t.v;
      }
#pragma unroll
      for (int j = 0; j < 2; ++j) {
        BF8 t;
        t.q = *(const uint4*)&Bs[wn + j * 16 + l16][h * 32 + quad * 8];
        bfr[j] = t.v;
      }
#pragma unroll
      for (int i = 0; i < 2; ++i)
#pragma unroll
        for (int j = 0; j < 2; ++j)
          acc[i][j] = __builtin_amdgcn_mfma_f32_16x16x32_bf16(af[i], bfr[j],
                                                              acc[i][j], 0, 0, 0);
    }
  }

#pragma unroll
  for (int j = 0; j < 2; ++j) {
    const int col = n0 + wn + j * 16 + l16;
    const float cb = isPD ? (C2F * bs[col]) : 0.f;
#pragma unroll
    for (int i = 0; i < 2; ++i) {
      const int row = m0 + wm + i * 16 + quad * 4;
#pragma unroll
      for (int r = 0; r < 4; ++r)
        out[(long)(row + r) * ldc + col] =
            __builtin_amdgcn_exp2f(C2F * acc[i][j][r] + cb);
    }
  }
}

// ---------------------------------------------------------------------------
// Combined logits + encT transpose, 1536 blocks (all co-resident):
//  bid < 1024:  enc[b][e][h] -> encT bf16 [b][h][e]  (BW-bound; only cgemm
//               consumes encT, so this overlaps the VALU-bound logits tree)
//  bid >= 1024: logits (packed f32x2 across dd-pairs, batched rcp),
//               written straight into attn (p0).
// ---------------------------------------------------------------------------
__global__ __launch_bounds__(256) void logits_enc_k(
    const float* __restrict__ Ee, const float* __restrict__ Ed,
    const float* __restrict__ v, float* __restrict__ p0,
    const float* __restrict__ enc, unsigned short* __restrict__ encT) {
  const int bid = blockIdx.x;
  const int tid = threadIdx.x;

  __shared__ unsigned short T[64][68];
  __shared__ float Eds[256][8];  // [a][dd] -- dd-pairs contiguous for f32x2
  __shared__ float vv[256];

  if (bid < 1024) {
    // ---- encT transpose path (old prep enc section) ----
    const int b = bid >> 8;
    const int tt = bid & 255;
    const float* in = enc + (long)b * ENC_LEN * ENC_H;
    unsigned short* out = encT + (long)b * ENC_H * ENC_LEN;
    const int bx = tt & 15;
    const int by = tt >> 4;
    const int r0 = by * 64;
    const int c0 = bx * 64;
    const int lr = tid >> 4;
    const int lc4 = (tid & 15) * 4;

#pragma unroll
    for (int p = 0; p < 4; ++p) {
      const int r = lr + p * 16;
      const float4 w = *(const float4*)&in[(long)(r0 + r) * ENC_H + c0 + lc4];
      ushort4 o;
      o.x = f2bf(w.x);
      o.y = f2bf(w.y);
      o.z = f2bf(w.z);
      o.w = f2bf(w.w);
      *(ushort4*)&T[r][lc4] = o;
    }
    __syncthreads();
#pragma unroll
    for (int p = 0; p < 4; ++p) {
      const int c = lr + p * 16;
      ushort4 o;
      o.x = T[lc4 + 0][c];
      o.y = T[lc4 + 1][c];
      o.z = T[lc4 + 2][c];
      o.w = T[lc4 + 3][c];
      *(ushort4*)&out[(long)(c0 + c) * ENC_LEN + r0 + lc4] = o;
    }
    return;
  }

  // ---- logits path ----
  const int lb = bid - 1024;  // 0..511 == old grid (4,32,4)
  const int e = (lb & 3) * 256 + tid;
  const int d0 = ((lb >> 2) & 31) * 8;
  const int b = lb >> 7;

#pragma unroll
  for (int dd = 0; dd < 8; ++dd)
    Eds[tid][dd] = Ed[(long)(b * DEC_LEN + d0 + dd) * ATTN_A + tid];
  vv[tid] = -2.0f * v[tid];
  __syncthreads();

  f32x2 acc2[4] = {{0.f, 0.f}, {0.f, 0.f}, {0.f, 0.f}, {0.f, 0.f}};
  const float* pe = Ee + (long)b * (ATTN_A * ENC_LEN) + e;

  float pn[8];
#pragma unroll
  for (int u = 0; u < 8; ++u) pn[u] = pe[(long)u * ENC_LEN];

  for (int a8 = 0; a8 < 256; a8 += 8) {
    float ee[8];
#pragma unroll
    for (int u = 0; u < 8; ++u) ee[u] = pn[u];
    const int an = (a8 + 8 < 256) ? (a8 + 8) : 0;
#pragma unroll
    for (int u = 0; u < 8; ++u) pn[u] = pe[(long)(an + u) * ENC_LEN];

    const float4 vL = *(const float4*)&vv[a8];
    const float4 vH = *(const float4*)&vv[a8 + 4];
    const float vs[8] = {vL.x, vL.y, vL.z, vL.w, vH.x, vH.y, vH.z, vH.w};

#pragma unroll
    for (int ddp = 0; ddp < 4; ++ddp) {
      f32x2 dn[8];
#pragma unroll
      for (int u = 0; u < 8; ++u) {
        const f32x2 ed2 = *(const f32x2*)&Eds[a8 + u][ddp * 2];
        dn[u] = ed2 * ee[u] + 1.0f;  // v_pk_fma_f32
      }
      const f32x2 pA = dn[0] * dn[1];
      const f32x2 pB = dn[2] * dn[3];
      const f32x2 pC = dn[4] * dn[5];
      const f32x2 pD = dn[6] * dn[7];
      const f32x2 sA = dn[1] * vs[0] + dn[0] * vs[1];
      const f32x2 sB = dn[3] * vs[2] + dn[2] * vs[3];
      const f32x2 sC = dn[5] * vs[4] + dn[4] * vs[5];
      const f32x2 sD = dn[7] * vs[6] + dn[6] * vs[7];
      const f32x2 P1 = pA * pB;
      const f32x2 P2 = pC * pD;
      const f32x2 S1 = sA * pB + sB * pA;
      const f32x2 S2 = sC * pD + sD * pC;
      const f32x2 num = S1 * P2 + S2 * P1;
      const f32x2 D = P1 * P2;
      f32x2 r;
      r.x = __builtin_amdgcn_rcpf(D.x);
      r.y = __builtin_amdgcn_rcpf(D.y);
      acc2[ddp] += num * r;
    }
  }

  const long base = ((long)(b * DEC_LEN + d0) * ENC_LEN) + e;
#pragma unroll
  for (int ddp = 0; ddp < 4; ++ddp) {
    p0[base + (long)(2 * ddp) * ENC_LEN] = acc2[ddp].x;
    p0[base + (long)(2 * ddp + 1) * ENC_LEN] = acc2[ddp].y;
  }
}

// ---------------------------------------------------------------------------
// Masked softmax over e, in place on p0 (attn output); bf16 copy for cgemm.
// NO max-subtraction: logits here = sum_a (-2 v_a)/den_a with den >= 1, so
// |l| <= 2*sum|v_a| (~8.2 for this input) -- exp is overflow-safe and
// softmax is shift-invariant. One shuffle-reduce instead of two.
// ---------------------------------------------------------------------------
__global__ __launch_bounds__(256) void softmax2_k(float* __restrict__ p0,
                                                  const float* __restrict__ mask,
                                                  unsigned short* __restrict__ attnB) {
  const int row = blockIdx.x;
  const int b = row >> 8;
  const int tid = threadIdx.x;
  float* rp = p0 + (long)row * ENC_LEN;
  const float* mp = mask + b * ENC_LEN;
  unsigned short* rb = attnB + (long)row * ENC_LEN;

  float l[4], m[4];
#pragma unroll
  for (int j = 0; j < 4; ++j) {
    l[j] = rp[tid + 256 * j];
    m[j] = mp[tid + 256 * j];
  }

  __shared__ float redsum[4];
  const int lane = tid & 63;
  const int wid = tid >> 6;

  const float LOG2E = 1.4426950408889634f;
  float p[4];
  float ts = 0.f;
#pragma unroll
  for (int j = 0; j < 4; ++j) {
    p[j] = __builtin_amdgcn_exp2f(l[j] * LOG2E) * m[j];
    ts += p[j];
  }
#pragma unroll
  for (int off = 1; off < 64; off <<= 1) ts += __shfl_xor(ts, off, 64);
  if (lane == 0) redsum[wid] = ts;
  __syncthreads();
  const float rsum = redsum[0] + redsum[1] + redsum[2] + redsum[3];

  const float inv = 1.0f / rsum;
#pragma unroll
  for (int j = 0; j < 4; ++j) {
    const float w = p[j] * inv;
    rp[tid + 256 * j] = w;
    rb[tid + 256 * j] = f2bf(w);
  }
}

// ---------------------------------------------------------------------------
// ctx GEMM, full K=1024: ctx[b][d][h] = attnB @ encT. grid (16, 4, 4) = 256
// blocks = exactly 1/CU. BK=64 / padded-LDS / b128 structure.
// ---------------------------------------------------------------------------
__global__ __launch_bounds__(256) void cgemm(const unsigned short* __restrict__ attnB,
                                             const unsigned short* __restrict__ encT,
                                             float* __restrict__ ctx) {
  __shared__ unsigned short As[64][72];
  __shared__ unsigned short Bs[64][72];

  const int b = blockIdx.z;
  const unsigned short* A = attnB + (long)b * DEC_LEN * ENC_LEN;
  const unsigned short* BT = encT + (long)b * ENC_H * ENC_LEN;
  float* C = ctx + (long)b * DEC_LEN * ENC_H;

  const int tid = threadIdx.x;
  const int lane = tid & 63;
  const int wave = tid >> 6;
  const int quad = lane >> 4;
  const int l16 = lane & 15;
  const int wm = (wave >> 1) * 32;
  const int wn = (wave & 1) * 32;
  const int m0 = blockIdx.y * 64;
  const int n0 = blockIdx.x * 64;
  const int sr = tid >> 2;        // 0..63
  const int sk = (tid & 3) * 16;  // shorts

  f32x4 acc[2][2] = {{{0.f, 0.f, 0.f, 0.f}, {0.f, 0.f, 0.f, 0.f}},
                     {{0.f, 0.f, 0.f, 0.f}, {0.f, 0.f, 0.f, 0.f}}};

  const unsigned short* Ap = A + (long)(m0 + sr) * ENC_LEN + sk;
  const unsigned short* Bp = BT + (long)(n0 + sr) * ENC_LEN + sk;

  uint4 a0 = *(const uint4*)(Ap);
  uint4 a1 = *(const uint4*)(Ap + 8);
  uint4 b0 = *(const uint4*)(Bp);
  uint4 b1 = *(const uint4*)(Bp + 8);

  for (int k0 = 0; k0 < 1024; k0 += 64) {
    __syncthreads();
    *(uint4*)&As[sr][sk] = a0;
    *(uint4*)&As[sr][sk + 8] = a1;
    *(uint4*)&Bs[sr][sk] = b0;
    *(uint4*)&Bs[sr][sk + 8] = b1;
    const int kn = (k0 + 64 < 1024) ? (k0 + 64) : 0;
    a0 = *(const uint4*)(Ap + kn);
    a1 = *(const uint4*)(Ap + kn + 8);
    b0 = *(const uint4*)(Bp + kn);
    b1 = *(const uint4*)(Bp + kn + 8);
    __syncthreads();

#pragma unroll
    for (int h = 0; h < 2; ++h) {
      bf16x8 af[2], bfr[2];
#pragma unroll
      for (int i = 0; i < 2; ++i) {
        BF8 t;
        t.q = *(const uint4*)&As[wm + i * 16 + l16][h * 32 + quad * 8];
        af[i] = t.v;
      }
#pragma unroll
      for (int j = 0; j < 2; ++j) {
        BF8 t;
        t.q = *(const uint4*)&Bs[wn + j * 16 + l16][h * 32 + quad * 8];
        bfr[j] = t.v;
      }
#pragma unroll
      for (int i = 0; i < 2; ++i)
#pragma unroll
        for (int j = 0; j < 2; ++j)
          acc[i][j] = __builtin_amdgcn_mfma_f32_16x16x32_bf16(af[i], bfr[j],
                                                              acc[i][j], 0, 0, 0);
    }
  }

#pragma unroll
  for (int j = 0; j < 2; ++j) {
    const int col = n0 + wn + j * 16 + l16;
#pragma unroll
    for (int i = 0; i < 2; ++i) {
      const int row = m0 + wm + i * 16 + quad * 4;
#pragma unroll
      for (int r = 0; r < 4; ++r) C[(long)(row + r) * ENC_H + col] = acc[i][j][r];
    }
  }
}

// ---------------------------------------------------------------------------
// Fallback fp32 path kernels (proven, used only if ws too small)
// ---------------------------------------------------------------------------
template <int OMODE, bool BIAS>
__global__ __launch_bounds__(256) void gemm64(const float* __restrict__ A,
                                              const float* __restrict__ B,
                                              const float* __restrict__ bias,
                                              float* __restrict__ C,
                                              int K, int lda, int ldb, int ldc,
                                              long sA, long sB, long sC) {
  const int bz = blockIdx.z;
  A += (long)bz * sA;
  B += (long)bz * sB;
  C += (long)bz * sC;

  const int tid = threadIdx.x;
  const int tx = tid & 15;
  const int ty = tid >> 4;

  __shared__ float As2[16][64];
  __shared__ float Bs2[16][64];

  float acc[4][4];
#pragma unroll
  for (int i = 0; i < 4; ++i)
#pragma unroll
    for (int j = 0; j < 4; ++j) acc[i][j] = 0.f;

  const int ar = tid >> 2;
  const int ak4 = (tid & 3) << 2;
  const int br = tid >> 4;
  const int bn4 = (tid & 15) << 2;

  const float* Aload = A + (long)(blockIdx.y * 64 + ar) * lda + ak4;
  const float* Bload = B + (long)br * ldb + blockIdx.x * 64 + bn4;

  for (int k0 = 0; k0 < K; k0 += 16) {
    const float4 av = *(const float4*)(Aload + k0);
    const float4 bv = *(const float4*)(Bload + (long)k0 * ldb);
    __syncthreads();
    As2[ak4 + 0][ar] = av.x;
    As2[ak4 + 1][ar] = av.y;
    As2[ak4 + 2][ar] = av.z;
    As2[ak4 + 3][ar] = av.w;
    *(float4*)&Bs2[br][bn4] = bv;
    __syncthreads();
#pragma unroll
    for (int kk = 0; kk < 16; ++kk) {
      const float4 a4 = *(const float4*)&As2[kk][ty << 2];
      const float4 b4 = *(const float4*)&Bs2[kk][tx << 2];
      const float am[4] = {a4.x, a4.y, a4.z, a4.w};
      const float bn[4] = {b4.x, b4.y, b4.z, b4.w};
#pragma unroll
      for (int i = 0; i < 4; ++i)
#pragma unroll
        for (int j = 0; j < 4; ++j) acc[i][j] = fmaf(am[i], bn[j], acc[i][j]);
    }
  }

  if (OMODE == 0) {
    const int row0 = blockIdx.y * 64 + (ty << 2);
    const int col0 = blockIdx.x * 64 + (tx << 2);
    float4 bb4 = make_float4(0.f, 0.f, 0.f, 0.f);
    if (BIAS) bb4 = *(const float4*)&bias[col0];
#pragma unroll
    for (int i = 0; i < 4; ++i) {
      float4 o;
      o.x = acc[i][0] + bb4.x;
      o.y = acc[i][1] + bb4.y;
      o.z = acc[i][2] + bb4.z;
      o.w = acc[i][3] + bb4.w;
      *(float4*)&C[(long)(row0 + i) * ldc + col0] = o;
    }
  } else {
#pragma unroll
    for (int i = 0; i < 4; ++i) {
      const int gr = blockIdx.y * 64 + (ty << 2) + i;
      const int b = gr >> 10;
      const int e = gr & 1023;
#pragma unroll
      for (int j = 0; j < 4; ++j) {
        const int col = blockIdx.x * 64 + (tx << 2) + j;
        C[(long)b * (ATTN_A * ENC_LEN) + (long)col * ENC_LEN + e] = acc[i][j];
      }
    }
  }
}

__global__ __launch_bounds__(256) void logits_fb(const float* __restrict__ peT,
                                                 const float* __restrict__ pd,
                                                 const float* __restrict__ v,
                                                 float* __restrict__ out) {
  const int tid = threadIdx.x;
  const int e = blockIdx.x * 256 + tid;
  const int d0 = blockIdx.y * 8;
  const int b = blockIdx.z;

  __shared__ float cpd[ATTN_A][8];
  __shared__ float vv[ATTN_A];

  {
    const int a = tid;
#pragma unroll
    for (int dd = 0; dd < 8; ++dd)
      cpd[a][dd] = C2F * pd[((b * DEC_LEN + d0 + dd) * ATTN_A) + a];
    vv[a] = -2.0f * v[a];
  }
  __syncthreads();

  float acc[8] = {0.f, 0.f, 0.f, 0.f, 0.f, 0.f, 0.f, 0.f};
  const float* pe = peT + (long)b * (ATTN_A * ENC_LEN) + e;

  for (int a = 0; a < ATTN_A; a += 4) {
    float pes[4];
#pragma unroll
    for (int u = 0; u < 4; ++u) pes[u] = pe[(long)(a + u) * ENC_LEN];
#pragma unroll
    for (int u = 0; u < 4; ++u) {
      const float cpe = C2F * pes[u];
      const float vu = vv[a + u];
      const float4 c0 = *(const float4*)&cpd[a + u][0];
      const float4 c1 = *(const float4*)&cpd[a + u][4];
      const float cd[8] = {c0.x, c0.y, c0.z, c0.w, c1.x, c1.y, c1.z, c1.w};
#pragma unroll
      for (int dd = 0; dd < 8; ++dd) {
        const float x = cd[dd] + cpe;
        const float ex = __builtin_amdgcn_exp2f(x);
        const float r = __builtin_amdgcn_rcpf(ex + 1.0f);
        acc[dd] = fmaf(vu, r, acc[dd]);
      }
    }
  }

  const long base = ((long)(b * DEC_LEN + d0) * ENC_LEN) + e;
#pragma unroll
  for (int dd = 0; dd < 8; ++dd) out[base + (long)dd * ENC_LEN] = acc[dd];
}

__global__ __launch_bounds__(256) void softmax_fb(float* __restrict__ attn,
                                                  const float* __restrict__ mask) {
  const int row = blockIdx.x;
  const int b = row >> 8;
  const int tid = threadIdx.x;
  float* rp = attn + (long)row * ENC_LEN;
  const float* mp = mask + b * ENC_LEN;

  float l[4], m[4];
#pragma unroll
  for (int j = 0; j < 4; ++j) {
    l[j] = rp[tid + 256 * j];
    m[j] = mp[tid + 256 * j];
  }

  __shared__ float redmax[4];
  __shared__ float redsum[4];
  const int lane = tid & 63;
  const int wid = tid >> 6;

  float tm = fmaxf(fmaxf(l[0], l[1]), fmaxf(l[2], l[3]));
#pragma unroll
  for (int off = 1; off < 64; off <<= 1) tm = fmaxf(tm, __shfl_xor(tm, off, 64));
  if (lane == 0) redmax[wid] = tm;
  __syncthreads();
  const float rmax = fmaxf(fmaxf(redmax[0], redmax[1]), fmaxf(redmax[2], redmax[3]));

  const float LOG2E = 1.4426950408889634f;
  float p[4];
  float ts = 0.f;
#pragma unroll
  for (int j = 0; j < 4; ++j) {
    p[j] = __builtin_amdgcn_exp2f((l[j] - rmax) * LOG2E) * m[j];
    ts += p[j];
  }
#pragma unroll
  for (int off = 1; off < 64; off <<= 1) ts += __shfl_xor(ts, off, 64);
  if (lane == 0) redsum[wid] = ts;
  __syncthreads();
  const float rsum = redsum[0] + redsum[1] + redsum[2] + redsum[3];

  const float inv = 1.0f / rsum;
#pragma unroll
  for (int j = 0; j < 4; ++j) rp[tid + 256 * j] = p[j] * inv;
}

// ---------------------------------------------------------------------------
extern "C" void kernel_launch(void* const* d_in, const int* in_sizes, int n_in,
                              void* d_out, int out_size, void* d_ws, size_t ws_size,
                              hipStream_t stream) {
  const float* enc = (const float*)d_in[0];
  const float* dec = (const float*)d_in[1];
  const float* mask = (const float*)d_in[2];
  const float* Wh = (const float*)d_in[3];
  const float* Ws = (const float*)d_in[4];
  const float* bs = (const float*)d_in[5];
  const float* v = (const float*)d_in[6];

  float* ctx = (float*)d_out;                      // [4,256,1024]
  float* attn = ctx + (long)BB * DEC_LEN * ENC_H;  // [4,256,1024]

  // ws layout (fast path):
  //  Ed   f32 [1024][256]             1 MB   exp2(C2*(dec.Ws+bs))
  //  Ee   f32 [4][256a][1024e]        4 MB   exp2(C2*(enc.Wh)), a-major
  //  encT bf16 [4][1024h][1024e]      8 MB
  //  WhT/WsT bf16 [256][1024]         1 MB
  //  encB bf16 [4][1024e][1024h]      8 MB
  //  decB bf16 [1024][1024]           2 MB
  //  attnB bf16 [4][256][1024]        2 MB
  const long N_ED = 1024L * ATTN_A;
  const long N_EE = (long)BB * ATTN_A * ENC_LEN;
  const long N_ENC = (long)BB * ENC_H * ENC_LEN;   // bf16 elems (encT / encB)
  const long N_W = (long)ATTN_A * ENC_H;           // bf16 elems per weight
  const long N_DEC = 1024L * ENC_H;                // bf16 elems (decB)
  const long N_ATT = (long)BB * DEC_LEN * ENC_LEN; // bf16 elems (attnB)
  const size_t FAST_WS =
      (N_ED + N_EE) * 4 + (N_ENC + 2 * N_W + N_ENC + N_DEC + N_ATT) * 2;

  if (ws_size >= FAST_WS) {
    float* Ed = (float*)d_ws;
    float* Ee = Ed + N_ED;
    unsigned short* encT = (unsigned short*)(Ee + N_EE);
    unsigned short* WhT = encT + N_ENC;
    unsigned short* WsT = WhT + N_W;
    unsigned short* encB = WsT + N_W;
    unsigned short* decB = encB + N_ENC;
    unsigned short* attnB = decB + N_DEC;

    // 1) weight transposes + encB/decB converts (encT deferred)
    prep_k<<<dim3(1408, 1, 1), 256, 0, stream>>>(Wh, Ws, enc, dec, WhT, WsT, encB,
                                                 decB);
    // 2) full-K projections, all-bf16 staging, exp2 epilogue
    pgemm<<<dim3(320, 1, 1), 256, 0, stream>>>(decB, encB, WsT, WhT, bs, Ed, Ee);
    // 3) logits (VALU-bound) overlapped with encT transpose (BW-bound)
    logits_enc_k<<<dim3(1536, 1, 1), 256, 0, stream>>>(Ee, Ed, v, attn, enc, encT);
    // 4) masked softmax (no max pass) -> attn (fp32) + attnB (bf16)
    softmax2_k<<<dim3(BB * DEC_LEN, 1, 1), 256, 0, stream>>>(attn, mask, attnB);
    // 5) full-K ctx GEMM, direct write (256 blocks = 1/CU)
    cgemm<<<dim3(16, 4, BB), 256, 0, stream>>>(attnB, encT, ctx);
  } else {
    // fallback: proven fp32 path (5 MB ws)
    float* pd = (float*)d_ws;
    float* peT = pd + (long)BB * DEC_LEN * ATTN_A;

    gemm64<0, true><<<dim3(ATTN_A / 64, (BB * DEC_LEN) / 64, 1), 256, 0, stream>>>(
        dec, Ws, bs, pd, ENC_H, ENC_H, ATTN_A, ATTN_A, 0, 0, 0);
    gemm64<1, false><<<dim3(ATTN_A / 64, (BB * ENC_LEN) / 64, 1), 256, 0, stream>>>(
        enc, Wh, nullptr, peT, ENC_H, ENC_H, ATTN_A, 0, 0, 0, 0);
    logits_fb<<<dim3(ENC_LEN / 256, DEC_LEN / 8, BB), 256, 0, stream>>>(peT, pd, v,
                                                                        attn);
    softmax_fb<<<dim3(BB * DEC_LEN, 1, 1), 256, 0, stream>>>(attn, mask);
    gemm64<0, false><<<dim3(ENC_H / 64, DEC_LEN / 64, BB), 256, 0, stream>>>(
        attn, enc, nullptr, ctx, ENC_LEN, ENC_LEN, ENC_H, ENC_H,
        (long)DEC_LEN * ENC_LEN, (long)ENC_LEN * ENC_H, (long)DEC_LEN * ENC_H);
  }
}

// Round 6
// 129.451 us; speedup vs baseline: 1.0611x; 1.0611x over previous
//
#include <hip/hip_runtime.h>
#include <hip/hip_bf16.h>

// Problem dims (fixed by reference)
#define BB 4
#define ENC_LEN 1024
#define DEC_LEN 256
#define ENC_H 1024
#define ATTN_A 256

#define C2F 2.8853900817779268f  // 2*log2(e)

typedef short bf16x8 __attribute__((ext_vector_type(8)));
typedef float f32x4 __attribute__((ext_vector_type(4)));
typedef float f32x2 __attribute__((ext_vector_type(2)));
typedef unsigned int u32x2 __attribute__((ext_vector_type(2)));

union BF8 {
  uint4 q;
  bf16x8 v;
};

// fp32 -> bf16 round-to-nearest-even
static __device__ __forceinline__ unsigned short f2bf(float x) {
  union {
    float f;
    unsigned int u;
  } c;
  c.f = x;
  unsigned int r = c.u + 0x7FFFu + ((c.u >> 16) & 1u);
  return (unsigned short)(r >> 16);
}

// ---------------------------------------------------------------------------
// prep: all conversions/transposes in one dispatch (1408 blocks).
//  [0,64):      Wh [1024h][256a] -> WhT bf16 [256a][1024h]
//  [64,128):    Ws -> WsT
//  [128,1152):  enc[b][e][h] -> encT bf16 [b][h][e]  AND  encB bf16 [b][e][h]
//               (one global read feeds both outputs)
//  [1152,1408): dec -> decB bf16 (row-major convert only)
// ---------------------------------------------------------------------------
__global__ __launch_bounds__(256) void prep_k(
    const float* __restrict__ Wh, const float* __restrict__ Ws,
    const float* __restrict__ enc, const float* __restrict__ dec,
    unsigned short* __restrict__ WhT, unsigned short* __restrict__ WsT,
    unsigned short* __restrict__ encT, unsigned short* __restrict__ encB,
    unsigned short* __restrict__ decB) {
  __shared__ unsigned short T[64][68];
  const int wb = blockIdx.x;
  const int t = threadIdx.x;
  const int lr = t >> 4;
  const int lc4 = (t & 15) * 4;

  if (wb >= 1152) {
    // dec row-major bf16 convert: collapsed [1024][1024]
    const int q = wb - 1152;
    const int r0 = (q >> 4) * 64;
    const int c0 = (q & 15) * 64;
#pragma unroll
    for (int p = 0; p < 4; ++p) {
      const int r = lr + p * 16;
      const float4 v = *(const float4*)&dec[(long)(r0 + r) * ENC_H + c0 + lc4];
      ushort4 o;
      o.x = f2bf(v.x);
      o.y = f2bf(v.y);
      o.z = f2bf(v.z);
      o.w = f2bf(v.w);
      *(ushort4*)&decB[(long)(r0 + r) * ENC_H + c0 + lc4] = o;
    }
    return;
  }

  const float* in;
  unsigned short* out;
  unsigned short* out2 = nullptr;  // row-major bf16 copy (enc only)
  int R, C, bx, by;
  if (wb < 128) {
    in = (wb < 64) ? Wh : Ws;
    out = (wb < 64) ? WhT : WsT;
    const int tt = wb & 63;
    R = ENC_H;
    C = ATTN_A;
    bx = tt & 3;
    by = tt >> 2;
  } else {
    const int tt0 = wb - 128;
    const int b = tt0 >> 8;
    const int tt = tt0 & 255;
    in = enc + (long)b * ENC_LEN * ENC_H;
    out = encT + (long)b * ENC_H * ENC_LEN;
    out2 = encB + (long)b * ENC_LEN * ENC_H;
    R = ENC_LEN;
    C = ENC_H;
    bx = tt & 15;
    by = tt >> 4;
  }
  const int r0 = by * 64;
  const int c0 = bx * 64;

#pragma unroll
  for (int p = 0; p < 4; ++p) {
    const int r = lr + p * 16;
    const float4 v = *(const float4*)&in[(long)(r0 + r) * C + c0 + lc4];
    ushort4 o;
    o.x = f2bf(v.x);
    o.y = f2bf(v.y);
    o.z = f2bf(v.z);
    o.w = f2bf(v.w);
    *(ushort4*)&T[r][lc4] = o;
    if (out2) *(ushort4*)&out2[(long)(r0 + r) * C + c0 + lc4] = o;
  }
  __syncthreads();
#pragma unroll
  for (int p = 0; p < 4; ++p) {
    const int c = lr + p * 16;
    ushort4 o;
    o.x = T[lc4 + 0][c];
    o.y = T[lc4 + 1][c];
    o.z = T[lc4 + 2][c];
    o.w = T[lc4 + 3][c];
    *(ushort4*)&out[(long)(c0 + c) * R + r0 + lc4] = o;
  }
}

// ---------------------------------------------------------------------------
// Fused projection GEMM, full-K (1024), exp2 epilogue. 1-D grid, 320 blocks:
//  bid <  64:  Ed[bd][a]  = exp2(C2*(decB·WsT) + C2*bs[a])     [1024][256]
//  bid >= 64:  Ee[b][a][e] = exp2(C2*(WhT·encB^T))             [4][256][1024]
// Tile 64x64, BK=64, padded LDS [64][72] (16B-aligned rows -> ds_read_b128;
// bank stride 36 -> 2-way alias = free). All-bf16 operands (R3-proven).
// ---------------------------------------------------------------------------
__global__ __launch_bounds__(256) void pgemm(const unsigned short* __restrict__ decB,
                                             const unsigned short* __restrict__ encB,
                                             const unsigned short* __restrict__ WsT,
                                             const unsigned short* __restrict__ WhT,
                                             const float* __restrict__ bs,
                                             float* __restrict__ Ed,
                                             float* __restrict__ Ee) {
  __shared__ unsigned short As[64][72];
  __shared__ unsigned short Bs[64][72];

  const int bid = blockIdx.x;
  const bool isPD = bid < 64;
  const unsigned short* A;
  const unsigned short* BT;
  float* out;
  int ldc, m0, n0;
  if (isPD) {
    A = decB;
    BT = WsT;
    out = Ed;
    ldc = ATTN_A;
    m0 = (bid >> 2) * 64;
    n0 = (bid & 3) * 64;
  } else {
    const int q = bid - 64;
    const int b = q >> 6;
    const int r = q & 63;
    A = WhT;
    BT = encB + (long)b * ENC_LEN * ENC_H;
    out = Ee + (long)b * ATTN_A * ENC_LEN;
    ldc = ENC_LEN;
    m0 = (r >> 4) * 64;
    n0 = (r & 15) * 64;
  }

  const int tid = threadIdx.x;
  const int lane = tid & 63;
  const int wave = tid >> 6;
  const int quad = lane >> 4;
  const int l16 = lane & 15;
  const int wm = (wave >> 1) * 32;
  const int wn = (wave & 1) * 32;
  const int sr = tid >> 2;        // 0..63
  const int sk = (tid & 3) * 16;  // shorts: 0,16,32,48

  f32x4 acc[2][2] = {{{0.f, 0.f, 0.f, 0.f}, {0.f, 0.f, 0.f, 0.f}},
                     {{0.f, 0.f, 0.f, 0.f}, {0.f, 0.f, 0.f, 0.f}}};

  const unsigned short* Ap = A + (long)(m0 + sr) * ENC_H + sk;
  const unsigned short* Bp = BT + (long)(n0 + sr) * ENC_H + sk;

  uint4 a0 = *(const uint4*)(Ap);
  uint4 a1 = *(const uint4*)(Ap + 8);
  uint4 b0 = *(const uint4*)(Bp);
  uint4 b1 = *(const uint4*)(Bp + 8);

  for (int k0 = 0; k0 < 1024; k0 += 64) {
    __syncthreads();
    *(uint4*)&As[sr][sk] = a0;
    *(uint4*)&As[sr][sk + 8] = a1;
    *(uint4*)&Bs[sr][sk] = b0;
    *(uint4*)&Bs[sr][sk + 8] = b1;
    const int kn = (k0 + 64 < 1024) ? (k0 + 64) : 0;
    a0 = *(const uint4*)(Ap + kn);
    a1 = *(const uint4*)(Ap + kn + 8);
    b0 = *(const uint4*)(Bp + kn);
    b1 = *(const uint4*)(Bp + kn + 8);
    __syncthreads();

#pragma unroll
    for (int h = 0; h < 2; ++h) {
      bf16x8 af[2], bfr[2];
#pragma unroll
      for (int i = 0; i < 2; ++i) {
        BF8 t;
        t.q = *(const uint4*)&As[wm + i * 16 + l16][h * 32 + quad * 8];
        af[i] = t.v;
      }
#pragma unroll
      for (int j = 0; j < 2; ++j) {
        BF8 t;
        t.q = *(const uint4*)&Bs[wn + j * 16 + l16][h * 32 + quad * 8];
        bfr[j] = t.v;
      }
#pragma unroll
      for (int i = 0; i < 2; ++i)
#pragma unroll
        for (int j = 0; j < 2; ++j)
          acc[i][j] = __builtin_amdgcn_mfma_f32_16x16x32_bf16(af[i], bfr[j],
                                                              acc[i][j], 0, 0, 0);
    }
  }

#pragma unroll
  for (int j = 0; j < 2; ++j) {
    const int col = n0 + wn + j * 16 + l16;
    const float cb = isPD ? (C2F * bs[col]) : 0.f;
#pragma unroll
    for (int i = 0; i < 2; ++i) {
      const int row = m0 + wm + i * 16 + quad * 4;
#pragma unroll
      for (int r = 0; r < 4; ++r)
        out[(long)(row + r) * ldc + col] =
            __builtin_amdgcn_exp2f(C2F * acc[i][j][r] + cb);
    }
  }
}

// ---------------------------------------------------------------------------
// Logits: exp tables precomputed (Ed, Ee). den = Ed*Ee + 1; eight a-terms share
// ONE rcp per dd via pairwise fraction combining. PACKED across dd-pairs:
// the 8 decoder rows are independent identical trees, so Eds is stored
// transposed [a][8dd] and every tree op is an f32x2 (v_pk_fma_f32) across
// (dd, dd+1). Only the 2 component rcps stay scalar (trans pipe).
// Grid (4, 32, 4): each block = 256 e x 8 d x 256 a for one b.
// ---------------------------------------------------------------------------
__global__ __launch_bounds__(256) void logits_k(const float* __restrict__ Ee,
                                                const float* __restrict__ Ed,
                                                const float* __restrict__ v,
                                                float* __restrict__ p0) {
  const int tid = threadIdx.x;
  const int e = blockIdx.x * 256 + tid;
  const int d0 = blockIdx.y * 8;
  const int b = blockIdx.z;

  __shared__ float Eds[256][8];  // [a][dd] -- dd-pairs contiguous for f32x2
  __shared__ float vv[256];

#pragma unroll
  for (int dd = 0; dd < 8; ++dd)
    Eds[tid][dd] = Ed[(long)(b * DEC_LEN + d0 + dd) * ATTN_A + tid];
  vv[tid] = -2.0f * v[tid];
  __syncthreads();

  f32x2 acc2[4] = {{0.f, 0.f}, {0.f, 0.f}, {0.f, 0.f}, {0.f, 0.f}};
  const float* pe = Ee + (long)b * (ATTN_A * ENC_LEN) + e;

  float pn[8];
#pragma unroll
  for (int u = 0; u < 8; ++u) pn[u] = pe[(long)u * ENC_LEN];

  for (int a8 = 0; a8 < 256; a8 += 8) {
    float ee[8];
#pragma unroll
    for (int u = 0; u < 8; ++u) ee[u] = pn[u];
    const int an = (a8 + 8 < 256) ? (a8 + 8) : 0;
#pragma unroll
    for (int u = 0; u < 8; ++u) pn[u] = pe[(long)(an + u) * ENC_LEN];

    const float4 vL = *(const float4*)&vv[a8];
    const float4 vH = *(const float4*)&vv[a8 + 4];
    const float vs[8] = {vL.x, vL.y, vL.z, vL.w, vH.x, vH.y, vH.z, vH.w};

#pragma unroll
    for (int ddp = 0; ddp < 4; ++ddp) {
      f32x2 dn[8];
#pragma unroll
      for (int u = 0; u < 8; ++u) {
        const f32x2 ed2 = *(const f32x2*)&Eds[a8 + u][ddp * 2];
        dn[u] = ed2 * ee[u] + 1.0f;  // v_pk_fma_f32
      }
      // level 1: pair products + v-weighted pair sums (all packed)
      const f32x2 pA = dn[0] * dn[1];
      const f32x2 pB = dn[2] * dn[3];
      const f32x2 pC = dn[4] * dn[5];
      const f32x2 pD = dn[6] * dn[7];
      const f32x2 sA = dn[1] * vs[0] + dn[0] * vs[1];
      const f32x2 sB = dn[3] * vs[2] + dn[2] * vs[3];
      const f32x2 sC = dn[5] * vs[4] + dn[4] * vs[5];
      const f32x2 sD = dn[7] * vs[6] + dn[6] * vs[7];
      // level 2
      const f32x2 P1 = pA * pB;
      const f32x2 P2 = pC * pD;
      const f32x2 S1 = sA * pB + sB * pA;
      const f32x2 S2 = sC * pD + sD * pC;
      // level 3 + two component rcps (trans pipe)
      const f32x2 num = S1 * P2 + S2 * P1;
      const f32x2 D = P1 * P2;
      f32x2 r;
      r.x = __builtin_amdgcn_rcpf(D.x);
      r.y = __builtin_amdgcn_rcpf(D.y);
      acc2[ddp] += num * r;
    }
  }

  const long base = ((long)(b * DEC_LEN + d0) * ENC_LEN) + e;
#pragma unroll
  for (int ddp = 0; ddp < 4; ++ddp) {
    p0[base + (long)(2 * ddp) * ENC_LEN] = acc2[ddp].x;
    p0[base + (long)(2 * ddp + 1) * ENC_LEN] = acc2[ddp].y;
  }
}

// ---------------------------------------------------------------------------
// Masked softmax over e, in place on p0 (attn output); bf16 copy for cgemm.
// NO max-subtraction: logits = sum_a (-2 v_a)/den_a with den >= 1, so
// |l| <= 2*sum|v_a| (~8.2 for this input) -- exp2 is overflow-safe and
// softmax is shift-invariant. One shuffle-reduce instead of two.
// ---------------------------------------------------------------------------
__global__ __launch_bounds__(256) void softmax2_k(float* __restrict__ p0,
                                                  const float* __restrict__ mask,
                                                  unsigned short* __restrict__ attnB) {
  const int row = blockIdx.x;
  const int b = row >> 8;
  const int tid = threadIdx.x;
  float* rp = p0 + (long)row * ENC_LEN;
  const float* mp = mask + b * ENC_LEN;
  unsigned short* rb = attnB + (long)row * ENC_LEN;

  float l[4], m[4];
#pragma unroll
  for (int j = 0; j < 4; ++j) {
    l[j] = rp[tid + 256 * j];
    m[j] = mp[tid + 256 * j];
  }

  __shared__ float redsum[4];
  const int lane = tid & 63;
  const int wid = tid >> 6;

  const float LOG2E = 1.4426950408889634f;
  float p[4];
  float ts = 0.f;
#pragma unroll
  for (int j = 0; j < 4; ++j) {
    p[j] = __builtin_amdgcn_exp2f(l[j] * LOG2E) * m[j];
    ts += p[j];
  }
#pragma unroll
  for (int off = 1; off < 64; off <<= 1) ts += __shfl_xor(ts, off, 64);
  if (lane == 0) redsum[wid] = ts;
  __syncthreads();
  const float rsum = redsum[0] + redsum[1] + redsum[2] + redsum[3];

  const float inv = 1.0f / rsum;
#pragma unroll
  for (int j = 0; j < 4; ++j) {
    const float w = p[j] * inv;
    rp[tid + 256 * j] = w;
    rb[tid + 256 * j] = f2bf(w);
  }
}

// ---------------------------------------------------------------------------
// ctx GEMM, full K=1024: ctx[b][d][h] = attnB @ encT. grid (16, 4, 4) = 256
// blocks = exactly 1/CU. BK=64 / padded-LDS / b128 structure.
// ---------------------------------------------------------------------------
__global__ __launch_bounds__(256) void cgemm(const unsigned short* __restrict__ attnB,
                                             const unsigned short* __restrict__ encT,
                                             float* __restrict__ ctx) {
  __shared__ unsigned short As[64][72];
  __shared__ unsigned short Bs[64][72];

  const int b = blockIdx.z;
  const unsigned short* A = attnB + (long)b * DEC_LEN * ENC_LEN;
  const unsigned short* BT = encT + (long)b * ENC_H * ENC_LEN;
  float* C = ctx + (long)b * DEC_LEN * ENC_H;

  const int tid = threadIdx.x;
  const int lane = tid & 63;
  const int wave = tid >> 6;
  const int quad = lane >> 4;
  const int l16 = lane & 15;
  const int wm = (wave >> 1) * 32;
  const int wn = (wave & 1) * 32;
  const int m0 = blockIdx.y * 64;
  const int n0 = blockIdx.x * 64;
  const int sr = tid >> 2;        // 0..63
  const int sk = (tid & 3) * 16;  // shorts

  f32x4 acc[2][2] = {{{0.f, 0.f, 0.f, 0.f}, {0.f, 0.f, 0.f, 0.f}},
                     {{0.f, 0.f, 0.f, 0.f}, {0.f, 0.f, 0.f, 0.f}}};

  const unsigned short* Ap = A + (long)(m0 + sr) * ENC_LEN + sk;
  const unsigned short* Bp = BT + (long)(n0 + sr) * ENC_LEN + sk;

  uint4 a0 = *(const uint4*)(Ap);
  uint4 a1 = *(const uint4*)(Ap + 8);
  uint4 b0 = *(const uint4*)(Bp);
  uint4 b1 = *(const uint4*)(Bp + 8);

  for (int k0 = 0; k0 < 1024; k0 += 64) {
    __syncthreads();
    *(uint4*)&As[sr][sk] = a0;
    *(uint4*)&As[sr][sk + 8] = a1;
    *(uint4*)&Bs[sr][sk] = b0;
    *(uint4*)&Bs[sr][sk + 8] = b1;
    const int kn = (k0 + 64 < 1024) ? (k0 + 64) : 0;
    a0 = *(const uint4*)(Ap + kn);
    a1 = *(const uint4*)(Ap + kn + 8);
    b0 = *(const uint4*)(Bp + kn);
    b1 = *(const uint4*)(Bp + kn + 8);
    __syncthreads();

#pragma unroll
    for (int h = 0; h < 2; ++h) {
      bf16x8 af[2], bfr[2];
#pragma unroll
      for (int i = 0; i < 2; ++i) {
        BF8 t;
        t.q = *(const uint4*)&As[wm + i * 16 + l16][h * 32 + quad * 8];
        af[i] = t.v;
      }
#pragma unroll
      for (int j = 0; j < 2; ++j) {
        BF8 t;
        t.q = *(const uint4*)&Bs[wn + j * 16 + l16][h * 32 + quad * 8];
        bfr[j] = t.v;
      }
#pragma unroll
      for (int i = 0; i < 2; ++i)
#pragma unroll
        for (int j = 0; j < 2; ++j)
          acc[i][j] = __builtin_amdgcn_mfma_f32_16x16x32_bf16(af[i], bfr[j],
                                                              acc[i][j], 0, 0, 0);
    }
  }

#pragma unroll
  for (int j = 0; j < 2; ++j) {
    const int col = n0 + wn + j * 16 + l16;
#pragma unroll
    for (int i = 0; i < 2; ++i) {
      const int row = m0 + wm + i * 16 + quad * 4;
#pragma unroll
      for (int r = 0; r < 4; ++r) C[(long)(row + r) * ENC_H + col] = acc[i][j][r];
    }
  }
}

// ---------------------------------------------------------------------------
// Fallback fp32 path kernels (proven, used only if ws too small)
// ---------------------------------------------------------------------------
template <int OMODE, bool BIAS>
__global__ __launch_bounds__(256) void gemm64(const float* __restrict__ A,
                                              const float* __restrict__ B,
                                              const float* __restrict__ bias,
                                              float* __restrict__ C,
                                              int K, int lda, int ldb, int ldc,
                                              long sA, long sB, long sC) {
  const int bz = blockIdx.z;
  A += (long)bz * sA;
  B += (long)bz * sB;
  C += (long)bz * sC;

  const int tid = threadIdx.x;
  const int tx = tid & 15;
  const int ty = tid >> 4;

  __shared__ float As2[16][64];
  __shared__ float Bs2[16][64];

  float acc[4][4];
#pragma unroll
  for (int i = 0; i < 4; ++i)
#pragma unroll
    for (int j = 0; j < 4; ++j) acc[i][j] = 0.f;

  const int ar = tid >> 2;
  const int ak4 = (tid & 3) << 2;
  const int br = tid >> 4;
  const int bn4 = (tid & 15) << 2;

  const float* Aload = A + (long)(blockIdx.y * 64 + ar) * lda + ak4;
  const float* Bload = B + (long)br * ldb + blockIdx.x * 64 + bn4;

  for (int k0 = 0; k0 < K; k0 += 16) {
    const float4 av = *(const float4*)(Aload + k0);
    const float4 bv = *(const float4*)(Bload + (long)k0 * ldb);
    __syncthreads();
    As2[ak4 + 0][ar] = av.x;
    As2[ak4 + 1][ar] = av.y;
    As2[ak4 + 2][ar] = av.z;
    As2[ak4 + 3][ar] = av.w;
    *(float4*)&Bs2[br][bn4] = bv;
    __syncthreads();
#pragma unroll
    for (int kk = 0; kk < 16; ++kk) {
      const float4 a4 = *(const float4*)&As2[kk][ty << 2];
      const float4 b4 = *(const float4*)&Bs2[kk][tx << 2];
      const float am[4] = {a4.x, a4.y, a4.z, a4.w};
      const float bn[4] = {b4.x, b4.y, b4.z, b4.w};
#pragma unroll
      for (int i = 0; i < 4; ++i)
#pragma unroll
        for (int j = 0; j < 4; ++j) acc[i][j] = fmaf(am[i], bn[j], acc[i][j]);
    }
  }

  if (OMODE == 0) {
    const int row0 = blockIdx.y * 64 + (ty << 2);
    const int col0 = blockIdx.x * 64 + (tx << 2);
    float4 bb4 = make_float4(0.f, 0.f, 0.f, 0.f);
    if (BIAS) bb4 = *(const float4*)&bias[col0];
#pragma unroll
    for (int i = 0; i < 4; ++i) {
      float4 o;
      o.x = acc[i][0] + bb4.x;
      o.y = acc[i][1] + bb4.y;
      o.z = acc[i][2] + bb4.z;
      o.w = acc[i][3] + bb4.w;
      *(float4*)&C[(long)(row0 + i) * ldc + col0] = o;
    }
  } else {
#pragma unroll
    for (int i = 0; i < 4; ++i) {
      const int gr = blockIdx.y * 64 + (ty << 2) + i;
      const int b = gr >> 10;
      const int e = gr & 1023;
#pragma unroll
      for (int j = 0; j < 4; ++j) {
        const int col = blockIdx.x * 64 + (tx << 2) + j;
        C[(long)b * (ATTN_A * ENC_LEN) + (long)col * ENC_LEN + e] = acc[i][j];
      }
    }
  }
}

__global__ __launch_bounds__(256) void logits_fb(const float* __restrict__ peT,
                                                 const float* __restrict__ pd,
                                                 const float* __restrict__ v,
                                                 float* __restrict__ out) {
  const int tid = threadIdx.x;
  const int e = blockIdx.x * 256 + tid;
  const int d0 = blockIdx.y * 8;
  const int b = blockIdx.z;

  __shared__ float cpd[ATTN_A][8];
  __shared__ float vv[ATTN_A];

  {
    const int a = tid;
#pragma unroll
    for (int dd = 0; dd < 8; ++dd)
      cpd[a][dd] = C2F * pd[((b * DEC_LEN + d0 + dd) * ATTN_A) + a];
    vv[a] = -2.0f * v[a];
  }
  __syncthreads();

  float acc[8] = {0.f, 0.f, 0.f, 0.f, 0.f, 0.f, 0.f, 0.f};
  const float* pe = peT + (long)b * (ATTN_A * ENC_LEN) + e;

  for (int a = 0; a < ATTN_A; a += 4) {
    float pes[4];
#pragma unroll
    for (int u = 0; u < 4; ++u) pes[u] = pe[(long)(a + u) * ENC_LEN];
#pragma unroll
    for (int u = 0; u < 4; ++u) {
      const float cpe = C2F * pes[u];
      const float vu = vv[a + u];
      const float4 c0 = *(const float4*)&cpd[a + u][0];
      const float4 c1 = *(const float4*)&cpd[a + u][4];
      const float cd[8] = {c0.x, c0.y, c0.z, c0.w, c1.x, c1.y, c1.z, c1.w};
#pragma unroll
      for (int dd = 0; dd < 8; ++dd) {
        const float x = cd[dd] + cpe;
        const float ex = __builtin_amdgcn_exp2f(x);
        const float r = __builtin_amdgcn_rcpf(ex + 1.0f);
        acc[dd] = fmaf(vu, r, acc[dd]);
      }
    }
  }

  const long base = ((long)(b * DEC_LEN + d0) * ENC_LEN) + e;
#pragma unroll
  for (int dd = 0; dd < 8; ++dd) out[base + (long)dd * ENC_LEN] = acc[dd];
}

__global__ __launch_bounds__(256) void softmax_fb(float* __restrict__ attn,
                                                  const float* __restrict__ mask) {
  const int row = blockIdx.x;
  const int b = row >> 8;
  const int tid = threadIdx.x;
  float* rp = attn + (long)row * ENC_LEN;
  const float* mp = mask + b * ENC_LEN;

  float l[4], m[4];
#pragma unroll
  for (int j = 0; j < 4; ++j) {
    l[j] = rp[tid + 256 * j];
    m[j] = mp[tid + 256 * j];
  }

  __shared__ float redmax[4];
  __shared__ float redsum[4];
  const int lane = tid & 63;
  const int wid = tid >> 6;

  float tm = fmaxf(fmaxf(l[0], l[1]), fmaxf(l[2], l[3]));
#pragma unroll
  for (int off = 1; off < 64; off <<= 1) tm = fmaxf(tm, __shfl_xor(tm, off, 64));
  if (lane == 0) redmax[wid] = tm;
  __syncthreads();
  const float rmax = fmaxf(fmaxf(redmax[0], redmax[1]), fmaxf(redmax[2], redmax[3]));

  const float LOG2E = 1.4426950408889634f;
  float p[4];
  float ts = 0.f;
#pragma unroll
  for (int j = 0; j < 4; ++j) {
    p[j] = __builtin_amdgcn_exp2f((l[j] - rmax) * LOG2E) * m[j];
    ts += p[j];
  }
#pragma unroll
  for (int off = 1; off < 64; off <<= 1) ts += __shfl_xor(ts, off, 64);
  if (lane == 0) redsum[wid] = ts;
  __syncthreads();
  const float rsum = redsum[0] + redsum[1] + redsum[2] + redsum[3];

  const float inv = 1.0f / rsum;
#pragma unroll
  for (int j = 0; j < 4; ++j) rp[tid + 256 * j] = p[j] * inv;
}

// ---------------------------------------------------------------------------
extern "C" void kernel_launch(void* const* d_in, const int* in_sizes, int n_in,
                              void* d_out, int out_size, void* d_ws, size_t ws_size,
                              hipStream_t stream) {
  const float* enc = (const float*)d_in[0];
  const float* dec = (const float*)d_in[1];
  const float* mask = (const float*)d_in[2];
  const float* Wh = (const float*)d_in[3];
  const float* Ws = (const float*)d_in[4];
  const float* bs = (const float*)d_in[5];
  const float* v = (const float*)d_in[6];

  float* ctx = (float*)d_out;                      // [4,256,1024]
  float* attn = ctx + (long)BB * DEC_LEN * ENC_H;  // [4,256,1024]

  // ws layout (fast path):
  //  Ed   f32 [1024][256]             1 MB   exp2(C2*(dec.Ws+bs))
  //  Ee   f32 [4][256a][1024e]        4 MB   exp2(C2*(enc.Wh)), a-major
  //  encT bf16 [4][1024h][1024e]      8 MB
  //  WhT/WsT bf16 [256][1024]         1 MB
  //  encB bf16 [4][1024e][1024h]      8 MB
  //  decB bf16 [1024][1024]           2 MB
  //  attnB bf16 [4][256][1024]        2 MB
  const long N_ED = 1024L * ATTN_A;
  const long N_EE = (long)BB * ATTN_A * ENC_LEN;
  const long N_ENC = (long)BB * ENC_H * ENC_LEN;   // bf16 elems (encT / encB)
  const long N_W = (long)ATTN_A * ENC_H;           // bf16 elems per weight
  const long N_DEC = 1024L * ENC_H;                // bf16 elems (decB)
  const long N_ATT = (long)BB * DEC_LEN * ENC_LEN; // bf16 elems (attnB)
  const size_t FAST_WS =
      (N_ED + N_EE) * 4 + (N_ENC + 2 * N_W + N_ENC + N_DEC + N_ATT) * 2;

  if (ws_size >= FAST_WS) {
    float* Ed = (float*)d_ws;
    float* Ee = Ed + N_ED;
    unsigned short* encT = (unsigned short*)(Ee + N_EE);
    unsigned short* WhT = encT + N_ENC;
    unsigned short* WsT = WhT + N_W;
    unsigned short* encB = WsT + N_W;
    unsigned short* decB = encB + N_ENC;
    unsigned short* attnB = decB + N_DEC;

    // 1) all transposes + bf16 conversions (one enc read -> encT + encB)
    prep_k<<<dim3(1408, 1, 1), 256, 0, stream>>>(Wh, Ws, enc, dec, WhT, WsT, encT,
                                                 encB, decB);
    // 2) full-K projections, all-bf16 staging, exp2 epilogue
    pgemm<<<dim3(320, 1, 1), 256, 0, stream>>>(decB, encB, WsT, WhT, bs, Ed, Ee);
    // 3) logits (packed f32x2 across dd-pairs), written straight into attn
    logits_k<<<dim3(4, 32, BB), 256, 0, stream>>>(Ee, Ed, v, attn);
    // 4) masked softmax (no max pass) -> attn (fp32) + attnB (bf16)
    softmax2_k<<<dim3(BB * DEC_LEN, 1, 1), 256, 0, stream>>>(attn, mask, attnB);
    // 5) full-K ctx GEMM, direct write (256 blocks = 1/CU)
    cgemm<<<dim3(16, 4, BB), 256, 0, stream>>>(attnB, encT, ctx);
  } else {
    // fallback: proven fp32 path (5 MB ws)
    float* pd = (float*)d_ws;
    float* peT = pd + (long)BB * DEC_LEN * ATTN_A;

    gemm64<0, true><<<dim3(ATTN_A / 64, (BB * DEC_LEN) / 64, 1), 256, 0, stream>>>(
        dec, Ws, bs, pd, ENC_H, ENC_H, ATTN_A, ATTN_A, 0, 0, 0);
    gemm64<1, false><<<dim3(ATTN_A / 64, (BB * ENC_LEN) / 64, 1), 256, 0, stream>>>(
        enc, Wh, nullptr, peT, ENC_H, ENC_H, ATTN_A, 0, 0, 0, 0);
    logits_fb<<<dim3(ENC_LEN / 256, DEC_LEN / 8, BB), 256, 0, stream>>>(peT, pd, v,
                                                                        attn);
    softmax_fb<<<dim3(BB * DEC_LEN, 1, 1), 256, 0, stream>>>(attn, mask);
    gemm64<0, false><<<dim3(ENC_H / 64, DEC_LEN / 64, BB), 256, 0, stream>>>(
        attn, enc, nullptr, ctx, ENC_LEN, ENC_LEN, ENC_H, ENC_H,
        (long)DEC_LEN * ENC_LEN, (long)ENC_LEN * ENC_H, (long)DEC_LEN * ENC_H);
  }
}